// Round 3
// baseline (1738.428 us; speedup 1.0000x reference)
//
#include <hip/hip_runtime.h>
#include <hip/hip_bf16.h>
#include <cstdint>
#include <cstddef>

// Problem constants
#define BSZ  256
#define TDIM 128
#define DDIM 256
#define HIDN 256
#define G3   768   // 3*HID

using bf16x8 = __attribute__((ext_vector_type(8))) short;   // 8 bf16 in 4 VGPRs
using f32x4  = __attribute__((ext_vector_type(4))) float;   // MFMA accumulator

__device__ __forceinline__ unsigned short f2bf(float f) {
  union { float f; unsigned u; } x; x.f = f;
  unsigned r = x.u + 0x7FFFu + ((x.u >> 16) & 1u);   // RNE, inputs are sane
  return (unsigned short)(r >> 16);
}
__device__ __forceinline__ float sigm(float x) {
  return __builtin_amdgcn_rcpf(1.f + __expf(-x));
}
__device__ __forceinline__ float tanh_f(float x) {
  float e = __expf(2.f * x);
  return 1.f - 2.f * __builtin_amdgcn_rcpf(e + 1.f);
}
__device__ __forceinline__ float gelu_f(float x) {
  return 0.5f * x * (1.f + erff(x * 0.70710678118654752f));
}

// ---------------- fp32 -> bf16 convert ----------------
__global__ __launch_bounds__(256) void cvt_bf16(const float* __restrict__ src,
                                                unsigned short* __restrict__ dst, int n4) {
  int i = blockIdx.x * 256 + threadIdx.x;
  if (i >= n4) return;
  float4 v = ((const float4*)src)[i];
  ushort4 o;
  o.x = f2bf(v.x); o.y = f2bf(v.y); o.z = f2bf(v.z); o.w = f2bf(v.w);
  ((ushort4*)dst)[i] = o;
}

// ---------------- bf16 -> fp32 expand (for Hout) ----------------
__global__ __launch_bounds__(256) void bf2f(const unsigned short* __restrict__ s,
                                            float* __restrict__ d, int n8) {
  int i = blockIdx.x * 256 + threadIdx.x;
  if (i >= n8) return;
  ushort4 a = ((const ushort4*)s)[i * 2];
  ushort4 b = ((const ushort4*)s)[i * 2 + 1];
  union { unsigned u; float f; } t;
  float4 o0, o1;
  t.u = ((unsigned)a.x) << 16; o0.x = t.f;
  t.u = ((unsigned)a.y) << 16; o0.y = t.f;
  t.u = ((unsigned)a.z) << 16; o0.z = t.f;
  t.u = ((unsigned)a.w) << 16; o0.w = t.f;
  t.u = ((unsigned)b.x) << 16; o1.x = t.f;
  t.u = ((unsigned)b.y) << 16; o1.y = t.f;
  t.u = ((unsigned)b.z) << 16; o1.z = t.f;
  t.u = ((unsigned)b.w) << 16; o1.w = t.f;
  ((float4*)d)[i * 2] = o0;
  ((float4*)d)[i * 2 + 1] = o1;
}

// ---------------- async global->LDS staging ----------------
#if defined(__has_builtin)
#if __has_builtin(__builtin_amdgcn_global_load_lds)
#define HAVE_GLL 1
#endif
#endif
#ifndef HAVE_GLL
#define HAVE_GLL 0
#endif

__device__ __forceinline__ void stage16(const unsigned short* gp,
                                        unsigned short* lbase, int lane) {
#if HAVE_GLL
  __builtin_amdgcn_global_load_lds((const __attribute__((address_space(1))) void*)gp,
                                   (__attribute__((address_space(3))) void*)lbase, 16, 0, 0);
#else
  *(bf16x8*)(lbase + lane * 8) = *(const bf16x8*)gp;
#endif
}

// ---------------- bf16 MFMA GEMM: C[m,n] = sum_k A[m,k]*B[n,k] (+bias, +gelu) ----------------
// 128x128 tile, BK=32, 256 threads (4 waves, each 64x64), chunk-major LDS (conflict-free b128).
// tiled!=0: Cf written in gru-tiled layout (see gru_rec): rows are (b*T+t), cols (g,w,t2,m16);
//   off = ((b>>4)*128+t)*12288 + ((c*32 + w*4 + (b&15)>>2)*16 + m16)*4 + ((b&15)&3), c=g*2+t2.
__global__ __launch_bounds__(256) void gemm_bf16(
    const unsigned short* __restrict__ A, int lda,
    const unsigned short* __restrict__ B, int ldb,
    const float* __restrict__ bias,
    float* __restrict__ Cf, unsigned short* __restrict__ Cbf,
    int K, int ldc, int do_gelu, int tiled)
{
  __shared__ unsigned short As[4096], Bs[4096];   // 8KB each: [chunk c][row r] 16B slots
  const int tid = threadIdx.x;
  const int w = tid >> 6, lane = tid & 63;
  const int m16 = lane & 15, quad = lane >> 4;
  const int m0 = blockIdx.y * 128, n0 = blockIdx.x * 128;
  const int wm = w >> 1, wn = w & 1;

  const f32x4 z4 = {0.f, 0.f, 0.f, 0.f};
  f32x4 acc[4][4];
#pragma unroll
  for (int i = 0; i < 4; ++i)
#pragma unroll
    for (int j = 0; j < 4; ++j) acc[i][j] = z4;

  const int nk = K >> 5;
  for (int kk = 0; kk < nk; ++kk) {
#pragma unroll
    for (int i = 0; i < 2; ++i) {
      const int r = i * 64 + lane;                 // row within tile
      stage16(A + (size_t)(m0 + r) * lda + kk * 32 + w * 8, &As[w * 1024 + i * 512], lane);
      stage16(B + (size_t)(n0 + r) * ldb + kk * 32 + w * 8, &Bs[w * 1024 + i * 512], lane);
    }
    __syncthreads();
    bf16x8 af[4], bfr[4];
#pragma unroll
    for (int i = 0; i < 4; ++i) {
      af[i]  = *(const bf16x8*)&As[quad * 1024 + (wm * 64 + i * 16 + m16) * 8];
      bfr[i] = *(const bf16x8*)&Bs[quad * 1024 + (wn * 64 + i * 16 + m16) * 8];
    }
#pragma unroll
    for (int i = 0; i < 4; ++i)
#pragma unroll
      for (int j = 0; j < 4; ++j)
        acc[i][j] = __builtin_amdgcn_mfma_f32_16x16x32_bf16(af[i], bfr[j], acc[i][j], 0, 0, 0);
    __syncthreads();
  }

#pragma unroll
  for (int i = 0; i < 4; ++i) {
    const int row0 = m0 + wm * 64 + i * 16 + quad * 4;
#pragma unroll
    for (int j = 0; j < 4; ++j) {
      const int col = n0 + wn * 64 + j * 16 + m16;
#pragma unroll
      for (int rg = 0; rg < 4; ++rg) {
        float v = acc[i][j][rg];
        if (bias) v += bias[col];
        if (do_gelu) v = gelu_f(v);
        if (tiled) {
          const int row = row0 + rg;
          const int b = row >> 7, tt = row & 127;
          const int g = col >> 8, wq = (col >> 5) & 7, t2 = (col >> 4) & 1, mm = col & 15;
          const int c = g * 2 + t2;
          const size_t off = ((size_t)((b >> 4) * 128 + tt)) * 12288
                           + (size_t)(((c * 32 + wq * 4 + ((b & 15) >> 2)) * 16 + mm) * 4 + (b & 3));
          Cf[off] = v;
        } else {
          const size_t off = (size_t)(row0 + rg) * ldc + col;
          if (Cf)  Cf[off] = v;
          if (Cbf) Cbf[off] = f2bf(v);
        }
      }
    }
  }
}

// ---------------- GRU recurrence (one layer) ----------------
// 16 blocks x 16 batch rows; 512 threads = 8 waves, wave w owns hidden cols [32w,32w+32).
// r,z weight fragments pinned in VGPRs via volatile loads (128 VGPRs, reused 128 steps);
// n-gate streamed from L2 (131 KB/step/CU). gi pre-tiled: 6 coalesced float4 loads/lane/step.
// h bf16 tile double-buffered in LDS, XOR chunk swizzle, all offsets precomputed.
__global__ __launch_bounds__(512, 2) void gru_rec(
    const float* __restrict__ gi,            // tiled (see gemm_bf16), bih already added
    const unsigned short* __restrict__ Whh,  // (768, 256) bf16
    const float* __restrict__ bhh,           // (768,)
    unsigned short* __restrict__ Hbf)        // (BS,T,HID) bf16
{
  __shared__ unsigned short hs[2][16 * 256]; // [buf][row r][chunk c at (c^r)]
  const int tid = threadIdx.x;
  const int w = tid >> 6, lane = tid & 63;
  const int m16 = lane & 15, quad = lane >> 4;
  const int b0 = blockIdx.x * 16;
  const int colw = w * 32;

  for (int i = tid; i < 16 * 256; i += 512) hs[0][i] = 0;   // h0 = 0

  // r,z gate weight B-fragments pinned in VGPRs (volatile: no rematerialization)
  bf16x8 wreg[2][2][8];
#pragma unroll
  for (int g = 0; g < 2; ++g)
#pragma unroll
    for (int t2 = 0; t2 < 2; ++t2)
#pragma unroll
      for (int kk = 0; kk < 8; ++kk)
        wreg[g][t2][kk] = *(const volatile bf16x8*)&Whh[(size_t)(g * 256 + colw + t2 * 16 + m16) * 256
                                                         + kk * 32 + quad * 8];

  // n-gate streamed: per-lane base pointers
  const unsigned short* Wn0 = &Whh[(size_t)(512 + colw + m16) * 256 + quad * 8];
  const unsigned short* Wn1 = Wn0 + 16 * 256;

  float bb_[3][2];
#pragma unroll
  for (int g = 0; g < 3; ++g)
#pragma unroll
    for (int t2 = 0; t2 < 2; ++t2)
      bb_[g][t2] = bhh[g * 256 + colw + t2 * 16 + m16];

  // precomputed LDS offsets (t-invariant)
  int rdoff[8];
#pragma unroll
  for (int kk = 0; kk < 8; ++kk)
    rdoff[kk] = m16 * 256 + (((kk * 4 + quad) ^ m16) * 8);
  int wroff0[4];
#pragma unroll
  for (int rg = 0; rg < 4; ++rg) {
    const int row = quad * 4 + rg;
    const int cb0 = w * 4 + (m16 >> 3);          // bit1 free -> t2 folds in via ^(t2<<4)
    wroff0[rg] = row * 256 + ((cb0 ^ row) * 8) + (m16 & 7);
  }
  // H store pointers (advance 256/step)
  unsigned short* hp[4];
#pragma unroll
  for (int rg = 0; rg < 4; ++rg)
    hp[rg] = Hbf + (size_t)(b0 + quad * 4 + rg) * (TDIM * HIDN) + colw + m16;
  // tiled gi pointer (advance 12288/step)
  const float* gp = gi + (size_t)blockIdx.x * 128 * 12288 + (w * 256 + quad * 64 + m16 * 4);

  float hreg[2][4] = {};
  const f32x4 z4 = {0.f, 0.f, 0.f, 0.f};
  __syncthreads();

  for (int t = 0; t < TDIM; ++t) {
    const unsigned short* hsr = hs[t & 1];
    unsigned short*       hsw = hs[(t + 1) & 1];

    float4 gc[6];
#pragma unroll
    for (int c = 0; c < 6; ++c) gc[c] = *(const float4*)(gp + c * 2048);
    gp += 12288;

    f32x4 acc[6];
#pragma unroll
    for (int g = 0; g < 6; ++g) acc[g] = z4;

#pragma unroll
    for (int kk = 0; kk < 8; ++kk) {
      const bf16x8 a  = *(const bf16x8*)&hsr[rdoff[kk]];
      const bf16x8 n0 = *(const bf16x8*)&Wn0[kk * 32];   // L2-resident stream
      const bf16x8 n1 = *(const bf16x8*)&Wn1[kk * 32];
      acc[0] = __builtin_amdgcn_mfma_f32_16x16x32_bf16(a, wreg[0][0][kk], acc[0], 0, 0, 0);
      acc[1] = __builtin_amdgcn_mfma_f32_16x16x32_bf16(a, wreg[0][1][kk], acc[1], 0, 0, 0);
      acc[2] = __builtin_amdgcn_mfma_f32_16x16x32_bf16(a, wreg[1][0][kk], acc[2], 0, 0, 0);
      acc[3] = __builtin_amdgcn_mfma_f32_16x16x32_bf16(a, wreg[1][1][kk], acc[3], 0, 0, 0);
      acc[4] = __builtin_amdgcn_mfma_f32_16x16x32_bf16(a, n0, acc[4], 0, 0, 0);
      acc[5] = __builtin_amdgcn_mfma_f32_16x16x32_bf16(a, n1, acc[5], 0, 0, 0);
    }

#pragma unroll
    for (int t2 = 0; t2 < 2; ++t2)
#pragma unroll
      for (int rg = 0; rg < 4; ++rg) {
        const float r = sigm(gc[t2][rg]     + acc[t2][rg]     + bb_[0][t2]);
        const float z = sigm(gc[2 + t2][rg] + acc[2 + t2][rg] + bb_[1][t2]);
        const float hn = acc[4 + t2][rg] + bb_[2][t2];
        const float n = tanh_f(gc[4 + t2][rg] + r * hn);
        float h = hreg[t2][rg];
        h = n + z * (h - n);                 // (1-z)*n + z*h
        hreg[t2][rg] = h;
        const unsigned short hb = f2bf(h);
        hsw[wroff0[rg] ^ (t2 << 4)] = hb;
        hp[rg][t2 * 16] = hb;
      }
#pragma unroll
    for (int rg = 0; rg < 4; ++rg) hp[rg] += 256;
    __syncthreads();   // h_{t+1} buffer complete before next step reads it
  }
}

// ---------------- contrastive loss + alpha ----------------
__global__ __launch_bounds__(256) void loss_k(
    const float* __restrict__ WC, const float* __restrict__ P,
    const int* __restrict__ neg, float* __restrict__ alpha, float* __restrict__ loss)
{
  const int t = blockIdx.x;                       // 0..126
  const int w = threadIdx.x >> 6, lane = threadIdx.x & 63;
  __shared__ float wls[4];
  float lsum = 0.f;
#pragma unroll 1
  for (int bi = 0; bi < 8; ++bi) {
    const int b = blockIdx.y * 32 + w * 8 + bi;
    const float4 wc4 = *(const float4*)&WC[(size_t)(b * TDIM + t) * DDIM + lane * 4];
    float s[16];
    {
      const float4 p4 = *(const float4*)&P[(size_t)(b * TDIM + t + 1) * DDIM + lane * 4];
      s[0] = wc4.x * p4.x + wc4.y * p4.y + wc4.z * p4.z + wc4.w * p4.w;
    }
#pragma unroll
    for (int n = 0; n < 15; ++n) {
      const int rb = neg[(t * 15 + n) * 256 + b];
      const float4 p4 = *(const float4*)&P[(size_t)(rb * TDIM + t + 1) * DDIM + lane * 4];
      s[n + 1] = wc4.x * p4.x + wc4.y * p4.y + wc4.z * p4.z + wc4.w * p4.w;
    }
#pragma unroll
    for (int n = 0; n < 16; ++n) {
      float v = s[n];
#pragma unroll
      for (int off = 32; off > 0; off >>= 1) v += __shfl_xor(v, off);
      s[n] = v * (1.f / 256.f);                   // mean over D
    }
    float mx = s[0];
#pragma unroll
    for (int n = 1; n < 16; ++n) mx = fmaxf(mx, s[n]);
    float se = 0.f;
#pragma unroll
    for (int n = 0; n < 16; ++n) se += __expf(s[n] - mx);
    lsum -= (s[0] - mx - __logf(se));             // -pos_ce
    if (t == TDIM - 2 && lane == 0) alpha[b] = s[0];   // alpha == sp[:,126]
  }
  if (lane == 0) wls[w] = lsum;
  __syncthreads();
  if (threadIdx.x == 0)
    atomicAdd(loss, (wls[0] + wls[1] + wls[2] + wls[3]) * (1.f / 256.f));
}

// ---------------- y = gelu(H[:,-1]@Wp1^T) @ Wp2^T (second half) ----------------
__global__ __launch_bounds__(256) void y_k(const float* __restrict__ Yh,
                                           const float* __restrict__ Wp2,
                                           float* __restrict__ y) {
  const int w = threadIdx.x >> 6, lane = threadIdx.x & 63;
  const int b = blockIdx.x * 4 + w;
  const float4 a = *(const float4*)&Yh[(size_t)b * 256 + lane * 4];
  const float4 q = *(const float4*)&Wp2[lane * 4];
  float s = a.x * q.x + a.y * q.y + a.z * q.z + a.w * q.w;
#pragma unroll
  for (int off = 32; off > 0; off >>= 1) s += __shfl_xor(s, off);
  if (lane == 0) y[b] = s;
}

// ---------------- launch ----------------
extern "C" void kernel_launch(void* const* d_in, const int* in_sizes, int n_in,
                              void* d_out, int out_size, void* d_ws, size_t ws_size,
                              hipStream_t stream) {
  (void)in_sizes; (void)n_in; (void)out_size; (void)ws_size;
  const float* P    = (const float*)d_in[0];
  const float* bih0 = (const float*)d_in[3];
  const float* bhh0 = (const float*)d_in[4];
  const float* bih1 = (const float*)d_in[7];
  const float* bhh1 = (const float*)d_in[8];

  char* ws = (char*)d_ws;
  float*          gi   = (float*)(ws + 0);                       // 100663296 B
  unsigned short* Xbf  = (unsigned short*)(ws + 100663296);      // 16777216 B (H1bf then Hbf)
  unsigned short* Pbf  = (unsigned short*)(ws + 117440512);      // 16777216 B (Pbf then G1bf)
  float*          WC   = (float*)(ws + 134217728);               // 33554432 B
  unsigned short* wb   = (unsigned short*)(ws + 167772160);      // 2097152 B of bf16 weights
  unsigned short* wih0b = wb;
  unsigned short* whh0b = wb + 196608;
  unsigned short* wih1b = wb + 393216;
  unsigned short* whh1b = wb + 589824;
  unsigned short* wbW   = wb + 786432;
  unsigned short* wp1b  = wb + 851968;
  unsigned short* wr1b  = wb + 917504;
  unsigned short* wr2b  = wb + 983040;
  float*          Yh   = (float*)(ws + 169869312);               // 262144 B

  float* out  = (float*)d_out;
  float* Hout = out;                  // 8388608
  float* Yout = out + 8388608;        // 256
  float* Rout = out + 8388864;        // 8388608
  float* Aout = out + 16777472;       // 256
  float* Lout = out + 16777728;       // 1

  cvt_bf16<<<8192, 256, 0, stream>>>(P, Pbf, 2097152);
  cvt_bf16<<<192, 256, 0, stream>>>((const float*)d_in[1], wih0b, 49152);
  cvt_bf16<<<192, 256, 0, stream>>>((const float*)d_in[2], whh0b, 49152);
  cvt_bf16<<<192, 256, 0, stream>>>((const float*)d_in[5], wih1b, 49152);
  cvt_bf16<<<192, 256, 0, stream>>>((const float*)d_in[6], whh1b, 49152);
  cvt_bf16<<<64, 256, 0, stream>>>((const float*)d_in[9],  wbW,  16384);
  cvt_bf16<<<64, 256, 0, stream>>>((const float*)d_in[10], wp1b, 16384);
  cvt_bf16<<<64, 256, 0, stream>>>((const float*)d_in[12], wr1b, 16384);
  cvt_bf16<<<64, 256, 0, stream>>>((const float*)d_in[13], wr2b, 16384);

  dim3 thr(256);
  // gi0 = Pbf @ Wih0^T + bih0   (tiled output)
  gemm_bf16<<<dim3(6, 256), thr, 0, stream>>>(Pbf, 256, wih0b, 256, bih0, gi, nullptr, 256, 768, 0, 1);
  // layer 0 recurrence -> H1bf
  gru_rec<<<16, 512, 0, stream>>>(gi, whh0b, bhh0, Xbf);
  // gi1 = H1bf @ Wih1^T + bih1  (tiled output)
  gemm_bf16<<<dim3(6, 256), thr, 0, stream>>>(Xbf, 256, wih1b, 256, bih1, gi, nullptr, 256, 768, 0, 1);
  // layer 1 recurrence -> Hbf
  gru_rec<<<16, 512, 0, stream>>>(gi, whh1b, bhh1, Xbf);
  // Hout fp32 = expand(Hbf)
  bf2f<<<8192, 256, 0, stream>>>(Xbf, Hout, 2097152);
  // WCfull = H @ W^T
  gemm_bf16<<<dim3(2, 256), thr, 0, stream>>>(Xbf, 256, wbW, 256, nullptr, WC, nullptr, 256, 256, 0, 0);
  // G1 = gelu(H @ Wr1^T) (bf16 only, reuse Pbf)
  gemm_bf16<<<dim3(2, 256), thr, 0, stream>>>(Xbf, 256, wr1b, 256, nullptr, nullptr, Pbf, 256, 256, 1, 0);
  // R = G1 @ Wr2^T
  gemm_bf16<<<dim3(2, 256), thr, 0, stream>>>(Pbf, 256, wr2b, 256, nullptr, Rout, nullptr, 256, 256, 0, 0);
  // Yh = gelu(H[:,127,:] @ Wp1^T)  (A rows strided by T*HID)
  gemm_bf16<<<dim3(2, 2), thr, 0, stream>>>(Xbf + 127 * 256, 32768, wp1b, 256, nullptr, Yh, nullptr, 256, 256, 1, 0);
  y_k<<<64, 256, 0, stream>>>(Yh, (const float*)d_in[11], Yout);

  hipMemsetAsync(Lout, 0, 4, stream);
  loss_k<<<dim3(127, 8), thr, 0, stream>>>(WC, P, (const int*)d_in[14], Aout, Lout);
}